// Round 6
// baseline (158.900 us; speedup 1.0000x reference)
//
#include <hip/hip_runtime.h>

#define EG   16000   // graph edges
#define NG   1000    // graph_size (block rows/cols)
#define BB   32      // batch
#define SIZE 16000   // feature length (NG*16)

typedef float f32x4 __attribute__((ext_vector_type(4)));

// ---- binning pipeline: bucket edges by destination block-row t0 (proven r0) ----
__global__ void count_kernel(const int* __restrict__ rows, int* __restrict__ cnt) {
    int e = blockIdx.x * blockDim.x + threadIdx.x;
    if (e < EG) {
        int t0 = rows[e << 8] >> 4;   // rows[e*256] = t0*16 + 0
        atomicAdd(&cnt[t0], 1);
    }
}

__global__ void scan_kernel(const int* __restrict__ cnt,
                            int* __restrict__ bin_start,
                            int* __restrict__ cursor) {
    __shared__ int s[1024];
    int t = threadIdx.x;
    int c = (t < NG) ? cnt[t] : 0;
    s[t] = c;
    __syncthreads();
    for (int off = 1; off < 1024; off <<= 1) {
        int v = (t >= off) ? s[t - off] : 0;
        __syncthreads();
        s[t] += v;
        __syncthreads();
    }
    int incl = s[t];                  // inclusive scan
    if (t < NG) { bin_start[t] = incl - c; cursor[t] = incl - c; }
    if (t == 1023) bin_start[NG] = incl;   // total = EG
}

__global__ void scatter_kernel(const int* __restrict__ rows,
                               int* __restrict__ cursor,
                               int* __restrict__ edge_of) {
    int e = blockIdx.x * blockDim.x + threadIdx.x;
    if (e < EG) {
        int t0 = rows[e << 8] >> 4;
        int pos = atomicAdd(&cursor[t0], 1);
        edge_of[pos] = e;
    }
}

// ---- main kernel: one block per bin, 2 edges in flight, no atomics ----
// out[b, g*16+j] = bias + sum_{e in bin g} sum_i v_e[i*16+j] * x[b, t1_e*16+i]
// Per iteration pair: T14 split (issue globals -> compute prev -> ds_write -> 1 barrier).
// Slot s=tid>>7 accumulates even/odd edges; cross-slot LDS reduce at the end.
__global__ __launch_bounds__(256) void spmm_kernel(
    const float* __restrict__ wm, const float* __restrict__ wlv,
    const float* __restrict__ ew, const float* __restrict__ x,
    const float* __restrict__ bm, const float* __restrict__ blv,
    const float* __restrict__ eb, const int* __restrict__ cols,
    const int* __restrict__ edge_of, const int* __restrict__ bin_start,
    float* __restrict__ out)
{
    __shared__ f32x4 vt[2][2][64];    // [buf][slot][chunk] w tile, row-major i*16+j
    __shared__ f32x4 xs[2][2][128];   // [buf][slot][chunk] x tile, [b][i]

    int g   = blockIdx.x;
    int tid = threadIdx.x;
    int start = bin_start[g], end = bin_start[g + 1];
    int n  = end - start;
    int np = (n + 1) >> 1;            // edge pairs

    // compute role: slot cs, j-group jg (4 cols), batch cb
    int cs = tid >> 7;
    int jg = tid & 3;
    int cb = (tid >> 2) & 31;
    float acc0 = 0.f, acc1 = 0.f, acc2 = 0.f, acc3 = 0.f;

    // staging role: first 128 threads stage w (64 chunks/slot), rest stage x
    bool wrole = (tid < 128);
    int  ss = wrole ? (tid >> 6) : ((tid - 128) >> 6);
    int  sc = tid & 63;

    // index pipeline: (eA,eB,t1A,t1B) = pair to stage next; *_2 = one further
    int eA = -1, eB = -1, t1A = 0, t1B = 0;
    int eA2 = -1, eB2 = -1, t1A2 = 0, t1B2 = 0;

    auto load_idx = [&](int q, int& ea, int& ebv, int& ta, int& tb) {
        int i0 = start + (q << 1);
        ea  = (i0     < end) ? edge_of[i0]     : -1;
        ebv = (i0 + 1 < end) ? edge_of[i0 + 1] : -1;
        ta  = (ea  >= 0) ? (cols[(long)ea  << 8] >> 4) : 0;
        tb  = (ebv >= 0) ? (cols[(long)ebv << 8] >> 4) : 0;
    };

    f32x4 m4, l4, g4;     // w-role staged regs
    f32x4 xv0, xv1;       // x-role staged regs
    bool  sval = false;

    auto stage_issue = [&](int ea, int ebv, int ta, int tb) {
        int e  = ss ? ebv : ea;
        int t1 = ss ? tb  : ta;
        sval = (e >= 0);
        if (wrole) {
            long q = ((long)(sval ? e : 0) << 6) + sc;
            m4 = ((const f32x4*)wm)[q];
            l4 = ((const f32x4*)wlv)[q];
            g4 = ((const f32x4*)ew)[q];
        } else {
            const f32x4* x4 = (const f32x4*)x;
            int xrow = t1 << 2;                       // float4 offset of row t1*16
            xv0 = x4[(sc >> 2)        * (SIZE / 4) + xrow + (sc & 3)];
            int c1 = sc + 64;
            xv1 = x4[(c1 >> 2)        * (SIZE / 4) + xrow + (c1 & 3)];
        }
    };

    auto stage_write = [&](int buf) {
        if (wrole) {
            f32x4 v = {0.f, 0.f, 0.f, 0.f};
            if (sval) {
                v.x = g4.x * __expf(l4.x) + m4.x;
                v.y = g4.y * __expf(l4.y) + m4.y;
                v.z = g4.z * __expf(l4.z) + m4.z;
                v.w = g4.w * __expf(l4.w) + m4.w;
            }
            vt[buf][ss][sc] = v;
        } else {
            xs[buf][ss][sc]      = xv0;
            xs[buf][ss][sc + 64] = xv1;
        }
    };

    auto compute = [&](int buf) {
        f32x4 x0 = xs[buf][cs][(cb << 2) + 0];   // 4 x b128: full x row of batch cb
        f32x4 x1 = xs[buf][cs][(cb << 2) + 1];
        f32x4 x2 = xs[buf][cs][(cb << 2) + 2];
        f32x4 x3 = xs[buf][cs][(cb << 2) + 3];
        float xr[16] = { x0.x, x0.y, x0.z, x0.w,  x1.x, x1.y, x1.z, x1.w,
                         x2.x, x2.y, x2.z, x2.w,  x3.x, x3.y, x3.z, x3.w };
        #pragma unroll
        for (int i = 0; i < 16; ++i) {
            f32x4 w = vt[buf][cs][(i << 2) + jg];    // 16-lane broadcast, conflict-free
            float xi = xr[i];                         // static index after unroll
            acc0 += w.x * xi; acc1 += w.y * xi; acc2 += w.z * xi; acc3 += w.w * xi;
        }
    };

    // ---- prologue: stage pair 0, prefetch indices for pair 1 ----
    load_idx(0, eA, eB, t1A, t1B);
    stage_issue(eA, eB, t1A, t1B);
    load_idx(1, eA2, eB2, t1A2, t1B2);
    stage_write(0);
    __syncthreads();

    // ---- main loop ----
    for (int p = 0; p < np; ++p) {
        bool more = (p + 1 < np);
        if (more) {
            stage_issue(eA2, eB2, t1A2, t1B2);        // globals for pair p+1 (in flight)
            load_idx(p + 2, eA2, eB2, t1A2, t1B2);    // indices for pair p+2
        }
        compute(p & 1);                                // LDS-only: overlaps loads
        if (more) stage_write((p + 1) & 1);            // vmcnt wait lands here
        __syncthreads();
    }

    // ---- cross-slot reduce + fused bias + exclusive store (no atomics) ----
    f32x4* sred = &xs[0][0][0];                        // reuse (dead after last barrier)
    int lane128 = tid & 127;
    if (cs == 1) sred[lane128] = f32x4{acc0, acc1, acc2, acc3};
    __syncthreads();
    if (cs == 0) {
        f32x4 o = sred[lane128];
        acc0 += o.x; acc1 += o.y; acc2 += o.z; acc3 += o.w;
        int r0 = (g << 4) + (jg << 2);                 // 16B-aligned
        f32x4 b4 = *(const f32x4*)&bm[r0];
        f32x4 v4 = *(const f32x4*)&blv[r0];
        f32x4 e4 = *(const f32x4*)&eb[r0];
        f32x4 o4;
        o4.x = acc0 + (e4.x * __expf(v4.x) + b4.x);
        o4.y = acc1 + (e4.y * __expf(v4.y) + b4.y);
        o4.z = acc2 + (e4.z * __expf(v4.z) + b4.z);
        o4.w = acc3 + (e4.w * __expf(v4.w) + b4.w);
        *(f32x4*)&out[cb * SIZE + r0] = o4;
    }
    if (g == 0 && tid == 0) out[(long)BB * SIZE] = 0.0f;   // kl scalar
}

extern "C" void kernel_launch(void* const* d_in, const int* in_sizes, int n_in,
                              void* d_out, int out_size, void* d_ws, size_t ws_size,
                              hipStream_t stream) {
    const float* x   = (const float*)d_in[0];
    const float* wm  = (const float*)d_in[1];
    const float* wlv = (const float*)d_in[2];
    const float* bm  = (const float*)d_in[3];
    const float* blv = (const float*)d_in[4];
    const float* ew  = (const float*)d_in[5];
    const float* eb  = (const float*)d_in[6];
    const int* rows  = (const int*)d_in[7];
    const int* cols  = (const int*)d_in[8];
    float* out = (float*)d_out;

    char* ws = (char*)d_ws;
    int* cnt       = (int*)(ws);              // 1024 ints
    int* bin_start = (int*)(ws + 4096);       // 1001 ints
    int* cursor    = (int*)(ws + 8192);       // 1000 ints
    int* edge_of   = (int*)(ws + 12288);      // 16000 ints

    hipMemsetAsync(cnt, 0, 4096, stream);
    count_kernel<<<(EG + 255) / 256, 256, 0, stream>>>(rows, cnt);
    scan_kernel<<<1, 1024, 0, stream>>>(cnt, bin_start, cursor);
    scatter_kernel<<<(EG + 255) / 256, 256, 0, stream>>>(rows, cursor, edge_of);
    spmm_kernel<<<NG, 256, 0, stream>>>(wm, wlv, ew, x, bm, blv, eb, cols,
                                        edge_of, bin_start, out);
}

// Round 7
// 134.991 us; speedup vs baseline: 1.1771x; 1.1771x over previous
//
#include <hip/hip_runtime.h>

#define EG   16000   // graph edges
#define NG   1000    // graph_size (block rows/cols)
#define BB   32      // batch
#define SIZE 16000   // feature length (NG*16)
#define CAP  64      // bucket capacity per bin (Poisson(16): P(>64) ~ 1e-18)

typedef float f32x4 __attribute__((ext_vector_type(4)));

// ---- kernel 1: bucket edges by dest block-row; pack (e, t1) per entry ----
__global__ __launch_bounds__(256) void bucket_kernel(
    const int* __restrict__ rows, const int* __restrict__ cols,
    int* __restrict__ cnt, int* __restrict__ bucket)
{
    int e = blockIdx.x * 256 + threadIdx.x;
    if (e < EG) {
        int t0 = rows[(long)e << 8] >> 4;   // rows[e*256] = t0*16
        int t1 = cols[(long)e << 8] >> 4;   // cols[e*256] = t1*16
        int pos = atomicAdd(&cnt[t0], 1);
        if (pos < CAP) bucket[t0 * CAP + pos] = (e << 10) | t1;  // t1 < 1024
    }
}

// ---- kernel 2: one block per bin, 4 edges in flight (1 wave each), ----
// ---- no atomics: exclusive f32x4 stores with fused bias.           ----
// out[b, g*16+j] = bias + sum_{e in bin g} sum_i v_e[i*16+j] * x[b, t1_e*16+i]
// Thread (wave, lane): jg = lane&3 (4 cols), cb2 = lane>>2 (batches cb2, cb2+16).
// Per edge per thread: 16 w-b128 (conflict-free broadcast) + 8 x-b128 (pad-5,
// 2-way max). T14: issue next-edge globals -> compute current -> ds_write -> bar.
__global__ __launch_bounds__(256) void spmm_kernel(
    const float* __restrict__ wm, const float* __restrict__ wlv,
    const float* __restrict__ ew, const float* __restrict__ x,
    const float* __restrict__ bm, const float* __restrict__ blv,
    const float* __restrict__ eb,
    const int* __restrict__ cnt, const int* __restrict__ bucket,
    float* __restrict__ out)
{
    __shared__ f32x4 vt[2][4][64];    // [buf][slot][i*4+jg]  sampled weights
    __shared__ f32x4 xs[2][4][160];   // [buf][slot][b*5+q]   x rows, pad-5
    __shared__ int   sl[CAP];         // packed (e<<10)|t1 for this bin

    int g    = blockIdx.x;
    int tid  = threadIdx.x;
    int wave = tid >> 6;              // edge slot 0..3
    int lane = tid & 63;
    int jg   = lane & 3;
    int cb2  = lane >> 2;             // 0..15

    int n = cnt[g]; n = n < CAP ? n : CAP;
    if (tid < n) sl[tid] = bucket[g * CAP + tid];   // one parallel round
    __syncthreads();

    f32x4 acc0 = {0.f,0.f,0.f,0.f}, acc1 = {0.f,0.f,0.f,0.f};
    f32x4 m4, l4, g4, xv0, xv1;       // staged regs (in flight across compute)
    int iters = (n + 3) >> 2;
    bool vcur = false, vnxt = false;

    auto issue = [&](int idx) -> bool {     // global loads only (no LDS writes)
        bool val = idx < n;
        if (val) {                          // wave-uniform branch
            int pk = sl[idx];
            int e  = pk >> 10;
            int t1 = pk & 1023;
            long wq = ((long)e << 6) + lane;
            m4 = ((const f32x4*)wm)[wq];    // 3 x b128, coalesced 1KB/wave
            l4 = ((const f32x4*)wlv)[wq];
            g4 = ((const f32x4*)ew)[wq];
            const f32x4* x4 = (const f32x4*)x;
            int c0 = lane, c1 = lane + 64;  // chunk = (b = c>>2, q = c&3)
            xv0 = x4[(long)(c0 >> 2) * (SIZE/4) + (t1 << 2) + (c0 & 3)];
            xv1 = x4[(long)(c1 >> 2) * (SIZE/4) + (t1 << 2) + (c1 & 3)];
        }
        return val;
    };
    auto writeb = [&](int buf, bool val) {  // vmcnt wait lands here (T14)
        if (val) {
            f32x4 v;
            v.x = g4.x * __expf(l4.x) + m4.x;
            v.y = g4.y * __expf(l4.y) + m4.y;
            v.z = g4.z * __expf(l4.z) + m4.z;
            v.w = g4.w * __expf(l4.w) + m4.w;
            vt[buf][wave][lane] = v;        // chunk lane = (i=lane>>2, jg=lane&3)
            int c0 = lane, c1 = lane + 64;
            xs[buf][wave][(c0 >> 2) * 5 + (c0 & 3)] = xv0;
            xs[buf][wave][(c1 >> 2) * 5 + (c1 & 3)] = xv1;
        }
    };
    auto compute = [&](int buf, bool val) {
        if (!val) return;                   // wave-uniform; also NaN-safe skip
        f32x4 a0 = xs[buf][wave][ cb2       * 5 + 0];
        f32x4 a1 = xs[buf][wave][ cb2       * 5 + 1];
        f32x4 a2 = xs[buf][wave][ cb2       * 5 + 2];
        f32x4 a3 = xs[buf][wave][ cb2       * 5 + 3];
        f32x4 b0 = xs[buf][wave][(cb2 + 16) * 5 + 0];
        f32x4 b1 = xs[buf][wave][(cb2 + 16) * 5 + 1];
        f32x4 b2 = xs[buf][wave][(cb2 + 16) * 5 + 2];
        f32x4 b3 = xs[buf][wave][(cb2 + 16) * 5 + 3];
        float xra[16] = {a0.x,a0.y,a0.z,a0.w, a1.x,a1.y,a1.z,a1.w,
                         a2.x,a2.y,a2.z,a2.w, a3.x,a3.y,a3.z,a3.w};
        float xrb[16] = {b0.x,b0.y,b0.z,b0.w, b1.x,b1.y,b1.z,b1.w,
                         b2.x,b2.y,b2.z,b2.w, b3.x,b3.y,b3.z,b3.w};
        #pragma unroll
        for (int i = 0; i < 16; ++i) {
            f32x4 w = vt[buf][wave][(i << 2) + jg];  // 16-lane broadcast chunks
            acc0 += w * xra[i];             // 4 FMA (static index after unroll)
            acc1 += w * xrb[i];
        }
    };

    // prologue
    vcur = issue(wave);
    writeb(0, vcur);
    __syncthreads();
    // main loop: one barrier per 4-edge iteration
    for (int it = 0; it < iters; ++it) {
        bool more = (it + 1 < iters);
        if (more) vnxt = issue(((it + 1) << 2) + wave);  // globals in flight
        compute(it & 1, vcur);                            // LDS+VALU overlap
        if (more) writeb((it + 1) & 1, vnxt);
        __syncthreads();
        vcur = vnxt;
    }

    // ---- cross-slot reduce + fused bias + exclusive store (no atomics) ----
    f32x4* sred = &xs[0][0][0];            // overlay: xs dead after last barrier
    sred[(wave << 7) + (lane << 1) + 0] = acc0;
    sred[(wave << 7) + (lane << 1) + 1] = acc1;
    __syncthreads();
    if (tid < 128) {
        int cb  = tid >> 2;                // batch 0..31
        int jgf = tid & 3;
        int h   = cb >> 4;                 // which accumulator half
        int sl_ = ((cb & 15) << 2) + jgf;  // lane in slot
        f32x4 s = sred[(0 << 7) + (sl_ << 1) + h]
                + sred[(1 << 7) + (sl_ << 1) + h]
                + sred[(2 << 7) + (sl_ << 1) + h]
                + sred[(3 << 7) + (sl_ << 1) + h];
        int r0 = (g << 4) + (jgf << 2);    // 16B-aligned
        f32x4 b4 = *(const f32x4*)&bm[r0];
        f32x4 v4 = *(const f32x4*)&blv[r0];
        f32x4 e4 = *(const f32x4*)&eb[r0];
        f32x4 o;
        o.x = s.x + (e4.x * __expf(v4.x) + b4.x);
        o.y = s.y + (e4.y * __expf(v4.y) + b4.y);
        o.z = s.z + (e4.z * __expf(v4.z) + b4.z);
        o.w = s.w + (e4.w * __expf(v4.w) + b4.w);
        *(f32x4*)&out[(long)cb * SIZE + r0] = o;
    }
    if (g == 0 && tid == 0) out[(long)BB * SIZE] = 0.0f;   // kl scalar
}

extern "C" void kernel_launch(void* const* d_in, const int* in_sizes, int n_in,
                              void* d_out, int out_size, void* d_ws, size_t ws_size,
                              hipStream_t stream) {
    const float* x   = (const float*)d_in[0];
    const float* wm  = (const float*)d_in[1];
    const float* wlv = (const float*)d_in[2];
    const float* bm  = (const float*)d_in[3];
    const float* blv = (const float*)d_in[4];
    const float* ew  = (const float*)d_in[5];
    const float* eb  = (const float*)d_in[6];
    const int* rows  = (const int*)d_in[7];
    const int* cols  = (const int*)d_in[8];
    float* out = (float*)d_out;

    char* ws = (char*)d_ws;
    int* cnt    = (int*)(ws);             // 1000 ints (4KB slot)
    int* bucket = (int*)(ws + 4096);      // 1000*64 ints = 256KB

    hipMemsetAsync(cnt, 0, 4096, stream);
    bucket_kernel<<<(EG + 255) / 256, 256, 0, stream>>>(rows, cols, cnt, bucket);
    spmm_kernel<<<NG, 256, 0, stream>>>(wm, wlv, ew, x, bm, blv, eb,
                                        cnt, bucket, out);
}